// Round 8
// baseline (140.279 us; speedup 1.0000x reference)
//
#include <hip/hip_runtime.h>

// SSIM loss — round 8.
// R7 evidence: tile 47.4us, VALU 43%, HBM 25%, occ 52% (6 blocks/CU). Occupancy
// lever alone gave only -12% (54->47.4): issue-count + latency residual.
// R8: (1) cut VALU — stage1 fixed 6x42 thread decomposition (div once, x-check
//     hoisted, 4 unrolled iters) + float2-packed math everywhere the (sr,hr)
//     pair is symmetric (SLP -> v_pk_*_f32 candidates);
//     (2) TH 16->12: LDS 21.9KB -> 7 blocks/CU (87.5% cap), 492=41*12 exact.
// Structure: stage1 Y->LDS, stage2 h-sums (reg sliding), stage3 v-sums (reg
// sliding), per-block partials, tiny finalize. Fixed ~91.5us harness overhead
// observed across R3/R6/R7; controllable part is the tile kernel only.

#define IMG    512
#define SHAVE  10
#define OUTW   492            // 512 - 2*SHAVE
#define TW     32             // tile width  (x)
#define TH     12             // tile height (y)
#define HALO   5
#define REGW   (TW + 2*HALO)  // 42
#define REGH   (TH + 2*HALO)  // 22
#define NTX    16             // ceil(492/32)
#define NTY    41             // 492/12 exactly
#define NBATCH 16
#define NBLOCKS (NTX*NTY*NBATCH)   // 10496 = 256*41

__device__ __forceinline__ float2 f2(float x, float y) { return make_float2(x, y); }
__device__ __forceinline__ float2 add2(float2 a, float2 b) { return f2(a.x + b.x, a.y + b.y); }
__device__ __forceinline__ float2 sub2(float2 a, float2 b) { return f2(a.x - b.x, a.y - b.y); }
__device__ __forceinline__ float2 fma2(float2 a, float2 b, float2 c)
{ return f2(fmaf(a.x, b.x, c.x), fmaf(a.y, b.y, c.y)); }
__device__ __forceinline__ float2 fnma2(float2 a, float2 b, float2 c)   // c - a*b
{ return f2(fmaf(-a.x, b.x, c.x), fmaf(-a.y, b.y, c.y)); }
__device__ __forceinline__ float2 muls2(float s, float2 a) { return f2(s * a.x, s * a.y); }
__device__ __forceinline__ float2 fmas2(float s, float2 a, float2 c)
{ return f2(fmaf(s, a.x, c.x), fmaf(s, a.y, c.y)); }
__device__ __forceinline__ float2 clamp01_2(float2 a)
{ return f2(fminf(fmaxf(a.x, 0.f), 1.f), fminf(fmaxf(a.y, 0.f), 1.f)); }

__device__ __forceinline__ float ssim_term(float s, float h, float ss, float hh, float sh)
{
    const float C1 = 6.5025f;     // (0.01*255)^2
    const float C2 = 58.5225f;    // (0.03*255)^2
    const float inv121 = 1.0f / 121.0f;
    const float mu1   = s * inv121;
    const float mu2   = h * inv121;
    const float mu1sq = mu1 * mu1;
    const float mu2sq = mu2 * mu2;
    const float mu12  = mu1 * mu2;
    const float sig1  = ss * inv121 - mu1sq;
    const float sig2  = hh * inv121 - mu2sq;
    const float sig12 = sh * inv121 - mu12;
    const float num = (2.0f * mu12 + C1) * (2.0f * sig12 + C2);
    const float den = (mu1sq + mu2sq + C1) * (sig1 + sig2 + C2);
    return 1.0f - num / den;
}

__global__ __launch_bounds__(256)
void ssim_tile_kernel(const float* __restrict__ sr,
                      const float* __restrict__ hr,
                      double* __restrict__ partials)
{
    __shared__ float2 y2[REGH][REGW];        // (Ysr,Yhr), zero padded   7392 B
    __shared__ float4 hs4[REGH][TW + 1];     // h-sums (S,H,SS,HH)      11616 B
    __shared__ float  hsSH[REGH][TW + 1];    // h-sums (SH)              2904 B
    __shared__ double wsum[4];

    const int b   = blockIdx.z;
    const int oy0 = blockIdx.y * TH;
    const int ox0 = blockIdx.x * TW;
    const int tid = threadIdx.x;
    const int bid = blockIdx.x + NTX * (blockIdx.y + NTY * blockIdx.z);

    const float inv255 = 1.0f / 255.0f;
    const float w0 = 65.738f  / 256.0f;
    const float w1 = 129.057f / 256.0f;
    const float w2 = 25.064f  / 256.0f;

    const size_t cstride = (size_t)IMG * IMG;
    const size_t base    = (size_t)b * 3 * cstride;

    // ---- stage 1: global -> LDS, fused clip + RGB->Y, zero pad ----
    // Fixed decomposition: threads 0..251 = 6 rows x 42 cols per iteration,
    // 4 unrolled iterations cover rows 0..21 (last iter: rows 18..21 only).
    {
        const int tr = tid / REGW;           // computed once
        const int tc = tid - tr * REGW;
        const int sx = ox0 - HALO + tc;      // invariant across iters
        const bool xok = (unsigned)sx < (unsigned)OUTW;
        if (tid < 6 * REGW) {                // 252 active
#pragma unroll
            for (int it = 0; it < 4; ++it) {
                const int r = it * 6 + tr;   // 0..23
                if (r < REGH) {              // compile-time except last iter
                    const int sy = oy0 - HALO + r;
                    float2 y = f2(0.f, 0.f);
                    if (xok && (unsigned)sy < (unsigned)OUTW) {
                        const size_t idx = base + (size_t)(sy + SHAVE) * IMG + (sx + SHAVE);
                        float2 p0 = f2(sr[idx],               hr[idx]);
                        float2 p1 = f2(sr[idx +     cstride], hr[idx +     cstride]);
                        float2 p2 = f2(sr[idx + 2 * cstride], hr[idx + 2 * cstride]);
                        p0 = clamp01_2(muls2(inv255, p0));
                        p1 = clamp01_2(muls2(inv255, p1));
                        p2 = clamp01_2(muls2(inv255, p2));
                        y  = fmas2(w0, p0, fmas2(w1, p1, muls2(w2, p2)));
                    }
                    y2[r][tc] = y;
                }
            }
        }
    }
    __syncthreads();

    // ---- stage 2: horizontal 11-sums, products once + register sliding ----
    // 176 active threads: row r = tid>>3 (0..21), run of 4 cols c0 = (tid&7)*4.
    if (tid < 8 * REGH) {
        const int r  = tid >> 3;
        const int c0 = (tid & 7) * 4;
        float2 sm = f2(0.f, 0.f);            // (Σs, Σh)
        float2 sq = f2(0.f, 0.f);            // (Σs², Σh²)
        float  sh = 0.f;                     // Σs·h
#pragma unroll
        for (int j = 0; j < 11; ++j) {
            const float2 v = y2[r][c0 + j];
            sm = add2(sm, v);
            sq = fma2(v, v, sq);
            sh = fmaf(v.x, v.y, sh);
        }
        hs4[r][c0]  = make_float4(sm.x, sm.y, sq.x, sq.y);
        hsSH[r][c0] = sh;
#pragma unroll
        for (int k = 1; k < 4; ++k) {
            const float2 a = y2[r][c0 + 10 + k];   // incoming column
            const float2 d = y2[r][c0 + k - 1];    // outgoing column
            sm = add2(sm, sub2(a, d));
            sq = fma2(a, a, sq);
            sq = fnma2(d, d, sq);
            sh = fmaf(a.x, a.y, sh);
            sh = fmaf(-d.x, d.y, sh);
            hs4[r][c0 + k]  = make_float4(sm.x, sm.y, sq.x, sq.y);
            hsSH[r][c0 + k] = sh;
        }
    }
    __syncthreads();

    // ---- stage 3: vertical 11-sums via register sliding + SSIM ----
    // thread: output column oxl = tid&31, 2-row run r0 = (tid>>5)*2; r0<TH.
    const int oxl = tid & 31;
    const int r0  = (tid >> 5) * 2;          // 0,2,...,14; active if r0 < 12
    double local = 0.0;
    if (r0 < TH) {                           // 192 active threads
        const int ox = ox0 + oxl;
        float2 sm = f2(0.f, 0.f), sq = f2(0.f, 0.f);
        float  sh = 0.f;
#pragma unroll
        for (int u = 0; u < 11; ++u) {
            const float4 q = hs4[r0 + u][oxl];
            sm = add2(sm, f2(q.x, q.y));
            sq = add2(sq, f2(q.z, q.w));
            sh += hsSH[r0 + u][oxl];
        }
        // oy = oy0 + r0 (+1) is always < OUTW: 41*12 = 492 exactly.
        if (ox < OUTW) {
            local += (double)ssim_term(sm.x, sm.y, sq.x, sq.y, sh);
            const float4 qa = hs4[r0 + 11][oxl];   // incoming row
            const float4 qd = hs4[r0][oxl];        // outgoing row
            sm = add2(sm, sub2(f2(qa.x, qa.y), f2(qd.x, qd.y)));
            sq = add2(sq, sub2(f2(qa.z, qa.w), f2(qd.z, qd.w)));
            sh += hsSH[r0 + 11][oxl] - hsSH[r0][oxl];
            local += (double)ssim_term(sm.x, sm.y, sq.x, sq.y, sh);
        }
    }

    // ---- block reduction: wave shfl (64) -> LDS -> per-block partial ----
#pragma unroll
    for (int off = 32; off > 0; off >>= 1)
        local += __shfl_down(local, off, 64);
    const int lane = tid & 63;
    const int wv   = tid >> 6;
    if (lane == 0) wsum[wv] = local;
    __syncthreads();
    if (tid == 0)
        partials[bid] = wsum[0] + wsum[1] + wsum[2] + wsum[3];
}

__global__ __launch_bounds__(256)
void ssim_finalize(const double* __restrict__ partials,
                   float* __restrict__ out)
{
    __shared__ double wsum[4];
    const int tid = threadIdx.x;
    double local = 0.0;
#pragma unroll
    for (int i = 0; i < NBLOCKS / 256; ++i)     // 10496 = 256*41
        local += partials[tid + 256 * i];
#pragma unroll
    for (int off = 32; off > 0; off >>= 1)
        local += __shfl_down(local, off, 64);
    const int lane = tid & 63;
    const int wv   = tid >> 6;
    if (lane == 0) wsum[wv] = local;
    __syncthreads();
    if (tid == 0)
        out[0] = (float)((wsum[0] + wsum[1] + wsum[2] + wsum[3]) / (double)NBATCH);
}

extern "C" void kernel_launch(void* const* d_in, const int* in_sizes, int n_in,
                              void* d_out, int out_size, void* d_ws, size_t ws_size,
                              hipStream_t stream)
{
    const float* sr = (const float*)d_in[0];
    const float* hr = (const float*)d_in[1];
    double* partials = (double*)d_ws;          // 10496 doubles = 84 KB
    float* out = (float*)d_out;

    // partials are written unconditionally by every block -> no memset needed.
    dim3 grid(NTX, NTY, NBATCH);
    ssim_tile_kernel<<<grid, 256, 0, stream>>>(sr, hr, partials);
    ssim_finalize<<<1, 256, 0, stream>>>(partials, out);
}